// Round 6
// baseline (310.830 us; speedup 1.0000x reference)
//
#include <hip/hip_runtime.h>
#include <hip/hip_bf16.h>

typedef __attribute__((ext_vector_type(8))) short bf16x8;
typedef __attribute__((ext_vector_type(4))) float f32x4;

#define N_OBJ 1024
#define N_REL 1024
#define NB 32
#define D 512
#define VOCAB 2048
#define M_ROWS (NB * N_REL)          // 32768
#define PRE_BLK (VOCAB * D)          // 1048576 elems per PRE block (bf16)
#define WT_BLK (D * D)               // 262144 elems per transposed weight block

__device__ __forceinline__ ushort f2bf(float f) {
    union { float f; unsigned u; } v; v.f = f;
    unsigned u = v.u;
    unsigned r = (u + 0x7FFFu + ((u >> 16) & 1u)) >> 16;
    return (ushort)r;
}
__device__ __forceinline__ float bf2f(ushort h) {
    union { unsigned u; float f; } v; v.u = ((unsigned)h) << 16;
    return v.f;
}

// global -> LDS async 16B copy (m97 pattern; dest wave-uniform base + lane*16)
__device__ __forceinline__ void gload16(const ushort* g, const ushort* l) {
    __builtin_amdgcn_global_load_lds(
        (const __attribute__((address_space(1))) void*)(unsigned long long)(const void*)g,
        (__attribute__((address_space(3))) void*)(unsigned)(unsigned long long)(const void*)l,
        16, 0, 0);
}

// ================= GEMM body: 128x128 tile, BK=64, global_load_lds =================
// MODE 0: PREB[q] = EB @ WT[wtq[q]]      K=512, lda=512, bf16 out
// MODE 1: obj_f = sbjf @ Wobj0           K=512, lda=1024 -> featbuf hi
// MODE 2: rel_f = [sbjf|objf] @ [Wrel0;Wrel1]  K=1024 -> out0 + rel mask
template <int MODE>
__device__ __forceinline__ void gemm_body(
    int mt, int nt, int q, int tid,
    ushort* __restrict__ sA, ushort* __restrict__ sB,
    const ushort* __restrict__ A, const ushort* __restrict__ WT,
    ushort* __restrict__ PREB,
    const int* __restrict__ ssg_rel, const int* __restrict__ ssg_obj,
    const float* __restrict__ bias,
    ushort* __restrict__ featbuf, float* __restrict__ out0,
    float* __restrict__ out1) {
    const int m0 = mt * 128;
    constexpr int LDA = (MODE == 0) ? 512 : 1024;
    constexpr int KTOT = (MODE == 2) ? 1024 : 512;

    const ushort* BT0;
    const ushort* BT1 = nullptr;
    ushort* PREq = nullptr;
    if (MODE == 0) {
        const int wtq[9] = {0, 1, 2, 4, 5, 8, 9, 10, 11};
        BT0 = WT + (size_t)wtq[q] * WT_BLK + (size_t)nt * 128 * 512;
        PREq = PREB + (size_t)q * PRE_BLK;
    } else if (MODE == 1) {
        BT0 = WT + (size_t)3 * WT_BLK + (size_t)nt * 128 * 512;
    } else {
        BT0 = WT + (size_t)6 * WT_BLK + (size_t)nt * 128 * 512;
        BT1 = WT + (size_t)7 * WT_BLK + (size_t)nt * 128 * 512;
    }

    const int wave = tid >> 6;
    const int wm = wave >> 1, wn = wave & 1;
    const int lr = tid & 15, lk = (tid & 63) >> 4;

    f32x4 acc[4][4];
#pragma unroll
    for (int mi = 0; mi < 4; mi++)
#pragma unroll
        for (int ni = 0; ni < 4; ni++)
            acc[mi][ni] = (f32x4){0.f, 0.f, 0.f, 0.f};

    const ushort* Ag = A + (size_t)m0 * LDA;
    const int srow = tid >> 3;            // 0..31
    const int scol = (tid & 7) * 8;       // 0..56

    for (int k0 = 0; k0 < KTOT; k0 += 64) {
        const ushort* As = Ag + (size_t)srow * LDA + k0 + scol;
        const ushort* Bbase = (MODE == 2 && k0 >= 512) ? (BT1 + (k0 - 512)) : (BT0 + k0);
        const ushort* Bs = Bbase + (size_t)srow * 512 + scol;
#pragma unroll
        for (int i = 0; i < 4; i++)
            gload16(As + (size_t)i * 32 * LDA, &sA[i * 2048 + tid * 8]);
#pragma unroll
        for (int i = 0; i < 4; i++)
            gload16(Bs + (size_t)i * 32 * 512, &sB[i * 2048 + tid * 8]);
        __syncthreads();
#pragma unroll
        for (int ks = 0; ks < 2; ks++) {
            bf16x8 af[4], bfr[4];
#pragma unroll
            for (int mi = 0; mi < 4; mi++)
                af[mi] = *(const bf16x8*)&sA[(wm * 64 + mi * 16 + lr) * 64 + ks * 32 + lk * 8];
#pragma unroll
            for (int ni = 0; ni < 4; ni++)
                bfr[ni] = *(const bf16x8*)&sB[(wn * 64 + ni * 16 + lr) * 64 + ks * 32 + lk * 8];
#pragma unroll
            for (int mi = 0; mi < 4; mi++)
#pragma unroll
                for (int ni = 0; ni < 4; ni++)
                    acc[mi][ni] = __builtin_amdgcn_mfma_f32_16x16x32_bf16(af[mi], bfr[ni], acc[mi][ni], 0, 0, 0);
        }
        __syncthreads();
    }

    // ---- epilogue ----
    int* sIo  = (int*)sA;
    int* sRid = sIo + 128;
    if (MODE == 1 || MODE == 2) {
        if (tid < 128) {
            int R = m0 + tid;
            int rid = ssg_rel[R * 3 + 2];
            sRid[tid] = rid;
            if (MODE == 1) sIo[tid] = ssg_obj[(R & ~(N_OBJ - 1)) + ssg_rel[R * 3 + 1]];
            if (MODE == 2 && nt == 0) {
                int b = R >> 10, rr = R & (N_REL - 1);
                out1[(size_t)b * 3072 + 1024 + rr] = (rid == 1) ? 1.0f : 0.0f;
            }
        }
        __syncthreads();
    }

#pragma unroll
    for (int mi = 0; mi < 4; mi++) {
#pragma unroll
        for (int ni = 0; ni < 4; ni++) {
            int c = wn * 64 + ni * 16 + lr;
            int ch = nt * 128 + c;
#pragma unroll
            for (int j = 0; j < 4; j++) {
                int rl = wm * 64 + mi * 16 + lk * 4 + j;
                int R = m0 + rl;
                float v = acc[mi][ni][j];
                if (MODE == 0) {
                    PREq[(size_t)R * 512 + ch] = f2bf(v);
                } else if (MODE == 1) {
                    int rid = sRid[rl];
                    int io = sIo[rl];
                    float t = v + bf2f(PREB[(size_t)3 * PRE_BLK + (size_t)io * 512 + ch])
                                + bf2f(PREB[(size_t)4 * PRE_BLK + (size_t)rid * 512 + ch])
                                + bias[ch];
                    t = fmaxf(t, 0.f);
                    if (rid == 1) t = 0.f;
                    featbuf[(size_t)R * 1024 + 512 + ch] = f2bf(t);
                } else {  // MODE 2
                    int rid = sRid[rl];
                    float t = v + bf2f(PREB[(size_t)5 * PRE_BLK + (size_t)rid * 512 + ch])
                                + bias[ch];
                    t = fmaxf(t, 0.f);
                    if (rid == 1) t = 0.f;
                    int b = R >> 10, rr = R & (N_REL - 1);
                    out0[((size_t)(b * 3072 + 1024 + rr)) * 512 + ch] = t;
                }
            }
        }
    }
}

// ================= att features + obj/att masks (per-object, MODE0-dependent) ======
__device__ __forceinline__ void att_body(
    int Ro, int c4, const int* __restrict__ ssg_obj, const int* __restrict__ ssg_att,
    const ushort* __restrict__ PREB, const float* __restrict__ b_a,
    float* __restrict__ out0, float* __restrict__ out1) {
    int iv = ssg_obj[Ro];
    int bq = Ro >> 10, o = Ro & (N_OBJ - 1);
    int j0 = ssg_att[Ro * 4 + 0], j1 = ssg_att[Ro * 4 + 1];
    int j2 = ssg_att[Ro * 4 + 2], j3 = ssg_att[Ro * 4 + 3];
    float4 ba4 = ((const float4*)b_a)[c4];
    ushort4 q7 = ((const ushort4*)(PREB + (size_t)7 * PRE_BLK + (size_t)iv * 512))[c4];
    float bx = bf2f(q7.x) + ba4.x, by = bf2f(q7.y) + ba4.y;
    float bz = bf2f(q7.z) + ba4.z, bw = bf2f(q7.w) + ba4.w;
    int cnt = (j0 != 1) + (j1 != 1) + (j2 != 1) + (j3 != 1);
    float inv = cnt ? 1.0f / (float)cnt : 0.f;
    float sx = 0.f, sy = 0.f, sz = 0.f, sw = 0.f;
    const ushort* A2 = PREB + (size_t)8 * PRE_BLK;
#define ACC_ATT(J) if ((J) != 1) { \
        ushort4 a2 = ((const ushort4*)(A2 + (size_t)(J) * 512))[c4]; \
        sx += fmaxf(bx + bf2f(a2.x), 0.f); sy += fmaxf(by + bf2f(a2.y), 0.f); \
        sz += fmaxf(bz + bf2f(a2.z), 0.f); sw += fmaxf(bw + bf2f(a2.w), 0.f); }
    ACC_ATT(j0) ACC_ATT(j1) ACC_ATT(j2) ACC_ATT(j3)
#undef ACC_ATT
    float4 sv; sv.x = sx * inv; sv.y = sy * inv; sv.z = sz * inv; sv.w = sw * inv;
    ((float4*)out0)[((size_t)(bq * 3072 + 2048 + o)) * 128 + c4] = sv;
    if (c4 == 0) {
        out1[(size_t)bq * 3072 + o] = (iv == 1) ? 1.0f : 0.0f;
        out1[(size_t)bq * 3072 + 2048 + o] = (cnt == 0) ? 1.0f : 0.0f;
    }
}

// ================= node: init + CSR gather-reduce (needs feat complete) ============
__device__ __forceinline__ void node_body(
    int Ro, int c4, const int* __restrict__ ssg_obj,
    const int* __restrict__ offs, const int* __restrict__ lists,
    const ushort* __restrict__ feat, const ushort* __restrict__ PREB,
    const float* __restrict__ b_o, float* __restrict__ out0) {
    int iv = ssg_obj[Ro];
    int bq = Ro >> 10, o = Ro & (N_OBJ - 1);
    float4 bo4 = ((const float4*)b_o)[c4];
    ushort4 q6 = ((const ushort4*)(PREB + (size_t)6 * PRE_BLK + (size_t)iv * 512))[c4];
    float a0 = 0.f, a1 = 0.f, a2 = 0.f, a3 = 0.f;
    if (iv != 1) {
        a0 = fmaxf(bf2f(q6.x) + bo4.x, 0.f);
        a1 = fmaxf(bf2f(q6.y) + bo4.y, 0.f);
        a2 = fmaxf(bf2f(q6.z) + bo4.z, 0.f);
        a3 = fmaxf(bf2f(q6.w) + bo4.w, 0.f);
    }
    int s = offs[Ro], e = offs[Ro + 1];
    for (int i = s; i < e; ++i) {
        int ent = lists[i];
        ushort4 u = ((const ushort4*)(feat + (size_t)(ent >> 1) * 1024 + (ent & 1) * 512))[c4];
        a0 += bf2f(u.x); a1 += bf2f(u.y); a2 += bf2f(u.z); a3 += bf2f(u.w);
    }
    float4 r;
    r.x = a0 * (1.0f / 2048.0f); r.y = a1 * (1.0f / 2048.0f);
    r.z = a2 * (1.0f / 2048.0f); r.w = a3 * (1.0f / 2048.0f);
    ((float4*)out0)[((size_t)(bq * 3072 + o)) * 128 + c4] = r;
}

// ================= L1: cvt_emb + transpose_w + csr-zero (independent) ==============
__global__ __launch_bounds__(256)
void k_setup(const float* __restrict__ E, ushort* __restrict__ EB,
             const float* __restrict__ Wsbj, const float* __restrict__ Wobj,
             const float* __restrict__ Wrel, const float* __restrict__ Wo,
             const float* __restrict__ Wa, ushort* __restrict__ WT,
             int* __restrict__ cnt) {
    int blk = blockIdx.x, tid = threadIdx.x;
    if (blk < 1024) {                       // cvt_emb over 262144 float4 groups
        int i = blk * 256 + tid;
        float4 v = ((const float4*)E)[i];
        ushort4 o; o.x = f2bf(v.x); o.y = f2bf(v.y); o.z = f2bf(v.z); o.w = f2bf(v.w);
        ((ushort4*)EB)[i] = o;
    } else if (blk < 4096) {                // transpose: 3072 blocks
        __shared__ float s[32][33];
        int bb = blk - 1024;
        int q = bb >> 8, rem = bb & 255;
        int bx = rem & 15, by = rem >> 4;
        const float* src; int ro;
        if (q < 3)       { src = Wsbj; ro = q * 512; }
        else if (q < 6)  { src = Wobj; ro = (q - 3) * 512; }
        else if (q < 9)  { src = Wrel; ro = (q - 6) * 512; }
        else if (q == 9) { src = Wo;   ro = 0; }
        else             { src = Wa;   ro = (q - 10) * 512; }
        int tx = tid & 31, ty = tid >> 5;    // 32 x 8
        int kbase = by * 32, nbase = bx * 32;
#pragma unroll
        for (int i = 0; i < 4; i++) {
            int k = kbase + ty + i * 8;
            s[ty + i * 8][tx] = src[(size_t)(ro + k) * 512 + nbase + tx];
        }
        __syncthreads();
        ushort* dst = WT + (size_t)q * WT_BLK;
#pragma unroll
        for (int i = 0; i < 4; i++) {
            int n = nbase + ty + i * 8;
            dst[(size_t)n * 512 + kbase + tx] = f2bf(s[tx][ty + i * 8]);
        }
    } else {                                // zero cnt: 128 blocks
        cnt[(blk - 4096) * 256 + tid] = 0;
    }
}

// ================= L2: CSR count =================
__global__ void k_csr_count(const int* __restrict__ ssg_rel, int* __restrict__ cnt) {
    int r = blockIdx.x * 256 + threadIdx.x;
    int bb = r & ~(N_OBJ - 1);
    atomicAdd(&cnt[bb + ssg_rel[r * 3 + 0]], 1);
    atomicAdd(&cnt[bb + ssg_rel[r * 3 + 1]], 1);
}

// ================= L3: CSR scan =================
__global__ __launch_bounds__(1024)
void k_csr_scan(const int* __restrict__ cnt, int* __restrict__ offs, int* __restrict__ cursor) {
    __shared__ int part[1024];
    int t = threadIdx.x;
    int base = t * 32;
    int local[32];
    int sum = 0;
#pragma unroll
    for (int i = 0; i < 32; i++) { local[i] = sum; sum += cnt[base + i]; }
    part[t] = sum;
    __syncthreads();
    for (int d = 1; d < 1024; d <<= 1) {
        int v = (t >= d) ? part[t - d] : 0;
        __syncthreads();
        part[t] += v;
        __syncthreads();
    }
    int excl = (t == 0) ? 0 : part[t - 1];
#pragma unroll
    for (int i = 0; i < 32; i++) {
        int o = excl + local[i];
        offs[base + i] = o;
        cursor[base + i] = o;
    }
    if (t == 1023) offs[32768] = part[1023];
}

// ================= L4: MODE0 GEMM (576 blocks, internal skip) + CSR fill ===========
__global__ __launch_bounds__(256)
void k_pre_fill(const ushort* __restrict__ EB, const ushort* __restrict__ WT,
                ushort* __restrict__ PREB, const int* __restrict__ ssg_rel,
                int* __restrict__ cursor, int* __restrict__ lists) {
    int blk = blockIdx.x, tid = threadIdx.x;
    if (blk < 576) {
        int q = blk >> 6, mt = (blk >> 2) & 15, nt = blk & 3;
        if ((q == 2 || q == 4 || q == 5) && mt >= 8) return;  // rid-indexed: rows<1024
        __shared__ __attribute__((aligned(16))) ushort sA[128 * 64];
        __shared__ __attribute__((aligned(16))) ushort sB[128 * 64];
        gemm_body<0>(mt, nt, q, tid, sA, sB, EB, WT, PREB,
                     nullptr, nullptr, nullptr, nullptr, nullptr, nullptr);
    } else {
        int r = (blk - 576) * 256 + tid;
        int bb = r & ~(N_OBJ - 1);
        int p0 = atomicAdd(&cursor[bb + ssg_rel[r * 3 + 0]], 1);
        lists[p0] = r * 2;
        int p1 = atomicAdd(&cursor[bb + ssg_rel[r * 3 + 1]], 1);
        lists[p1] = r * 2 + 1;
    }
}

// ================= L5: sbj_f lookup layer =================
__global__ void k_sbj(const int* __restrict__ ssg_rel, const int* __restrict__ ssg_obj,
                      const ushort* __restrict__ PREB, const float* __restrict__ b_sbj,
                      ushort* __restrict__ featbuf) {
    int R = blockIdx.x * 2 + (threadIdx.x >> 7);
    int c4 = threadIdx.x & 127;
    int sid = ssg_rel[R * 3 + 0];
    int oid = ssg_rel[R * 3 + 1];
    int rid = ssg_rel[R * 3 + 2];
    int bb = R & ~(N_OBJ - 1);
    int is_ = ssg_obj[bb + sid];
    int io  = ssg_obj[bb + oid];
    ushort4 p1 = ((const ushort4*)(PREB + (size_t)is_ * 512))[c4];
    ushort4 p2 = ((const ushort4*)(PREB + (size_t)1 * PRE_BLK + (size_t)io * 512))[c4];
    ushort4 p3 = ((const ushort4*)(PREB + (size_t)2 * PRE_BLK + (size_t)rid * 512))[c4];
    float4 b  = ((const float4*)b_sbj)[c4];
    float4 v;
    v.x = fmaxf(bf2f(p1.x) + bf2f(p2.x) + bf2f(p3.x) + b.x, 0.f);
    v.y = fmaxf(bf2f(p1.y) + bf2f(p2.y) + bf2f(p3.y) + b.y, 0.f);
    v.z = fmaxf(bf2f(p1.z) + bf2f(p2.z) + bf2f(p3.z) + b.z, 0.f);
    v.w = fmaxf(bf2f(p1.w) + bf2f(p2.w) + bf2f(p3.w) + b.w, 0.f);
    if (rid == 1) { v.x = v.y = v.z = v.w = 0.f; }
    ushort4 o; o.x = f2bf(v.x); o.y = f2bf(v.y); o.z = f2bf(v.z); o.w = f2bf(v.w);
    *(ushort4*)&featbuf[(size_t)R * 1024 + c4 * 4] = o;
}

// ================= L6: MODE1 GEMM (1024 blocks) + att-pass (16384 blocks) ==========
__global__ __launch_bounds__(256)
void k_mode1_att(const ushort* __restrict__ feat, const ushort* __restrict__ WT,
                 ushort* __restrict__ PREB,
                 const int* __restrict__ ssg_rel, const int* __restrict__ ssg_obj,
                 const int* __restrict__ ssg_att,
                 const float* __restrict__ b_obj, const float* __restrict__ b_a,
                 ushort* __restrict__ featbuf,
                 float* __restrict__ out0, float* __restrict__ out1) {
    int blk = blockIdx.x, tid = threadIdx.x;
    if (blk < 1024) {
        int nb = (blk & 7) * 128 + (blk >> 3);   // XCD-chunked swizzle (1024 % 8 == 0)
        int mt = nb >> 2, nt = nb & 3;
        __shared__ __attribute__((aligned(16))) ushort sA[128 * 64];
        __shared__ __attribute__((aligned(16))) ushort sB[128 * 64];
        gemm_body<1>(mt, nt, 0, tid, sA, sB, feat, WT, PREB,
                     ssg_rel, ssg_obj, b_obj, featbuf, nullptr, nullptr);
    } else {
        int Ro = (blk - 1024) * 2 + (tid >> 7);
        att_body(Ro, tid & 127, ssg_obj, ssg_att, PREB, b_a, out0, out1);
    }
}

// ================= L7: MODE2 GEMM (1024 blocks) + node-pass (16384 blocks) =========
__global__ __launch_bounds__(256)
void k_mode2_node(const ushort* __restrict__ feat, const ushort* __restrict__ WT,
                  ushort* __restrict__ PREB,
                  const int* __restrict__ ssg_rel, const int* __restrict__ ssg_obj,
                  const int* __restrict__ offs, const int* __restrict__ lists,
                  const float* __restrict__ b_rel, const float* __restrict__ b_o,
                  float* __restrict__ out0, float* __restrict__ out1) {
    int blk = blockIdx.x, tid = threadIdx.x;
    if (blk < 1024) {
        int nb = (blk & 7) * 128 + (blk >> 3);
        int mt = nb >> 2, nt = nb & 3;
        __shared__ __attribute__((aligned(16))) ushort sA[128 * 64];
        __shared__ __attribute__((aligned(16))) ushort sB[128 * 64];
        gemm_body<2>(mt, nt, 0, tid, sA, sB, feat, WT, PREB,
                     ssg_rel, ssg_obj, b_rel, nullptr, out0, out1);
    } else {
        int Ro = (blk - 1024) * 2 + (tid >> 7);
        node_body(Ro, tid & 127, ssg_obj, offs, lists, feat, PREB, b_o, out0);
    }
}

extern "C" void kernel_launch(void* const* d_in, const int* in_sizes, int n_in,
                              void* d_out, int out_size, void* d_ws, size_t ws_size,
                              hipStream_t stream) {
    const int*   ssg_rel = (const int*)d_in[0];
    const int*   ssg_obj = (const int*)d_in[1];
    const int*   ssg_att = (const int*)d_in[2];
    const float* emb     = (const float*)d_in[3];
    const float* Wsbj    = (const float*)d_in[4];
    const float* bsbj    = (const float*)d_in[5];
    const float* Wobj    = (const float*)d_in[6];
    const float* bobj    = (const float*)d_in[7];
    const float* Wrel    = (const float*)d_in[8];
    const float* brel    = (const float*)d_in[9];
    const float* Wo      = (const float*)d_in[10];
    const float* bo      = (const float*)d_in[11];
    const float* Wa      = (const float*)d_in[12];
    const float* ba      = (const float*)d_in[13];

    float* out0 = (float*)d_out;
    float* out1 = out0 + (size_t)NB * 3072 * 512;

    char* w = (char*)d_ws;
    ushort* EB     = (ushort*)w; w += (size_t)VOCAB * D * 2;          //  2.0 MB
    ushort* WT     = (ushort*)w; w += (size_t)12 * WT_BLK * 2;        //  6.3 MB
    ushort* PREB   = (ushort*)w; w += (size_t)9 * PRE_BLK * 2;        // 18.9 MB (bf16)
    ushort* feat   = (ushort*)w; w += (size_t)M_ROWS * 1024 * 2;      // 67.1 MB  [sbjf | objf]
    int*    cnt    = (int*)   w; w += (size_t)32768 * 4;
    int*    offs   = (int*)   w; w += (size_t)32769 * 4;
    int*    cursor = (int*)   w; w += (size_t)32768 * 4;
    int*    lists  = (int*)   w; w += (size_t)65536 * 4;

    // L1: emb cvt + weight transpose + csr zero (independent)
    k_setup<<<dim3(4224), dim3(256), 0, stream>>>(emb, EB, Wsbj, Wobj, Wrel, Wo, Wa, WT, cnt);
    // L2: csr count
    k_csr_count<<<dim3(128), dim3(256), 0, stream>>>(ssg_rel, cnt);
    // L3: csr scan
    k_csr_scan<<<dim3(1), dim3(1024), 0, stream>>>(cnt, offs, cursor);
    // L4: PREB = E @ {9 blocks} (bf16)  ||  csr fill
    k_pre_fill<<<dim3(704), dim3(256), 0, stream>>>(EB, WT, PREB, ssg_rel, cursor, lists);
    // L5: sbj_f lookup layer -> feat lo
    k_sbj<<<dim3(M_ROWS / 2), dim3(256), 0, stream>>>(ssg_rel, ssg_obj, PREB, bsbj, feat);
    // L6: obj_f GEMM -> feat hi  ||  att features + obj/att masks
    k_mode1_att<<<dim3(1024 + M_ROWS / 2), dim3(256), 0, stream>>>(
        feat, WT, PREB, ssg_rel, ssg_obj, ssg_att, bobj, ba, feat, out0, out1);
    // L7: rel_f GEMM -> out0 + rel mask  ||  node gather -> out0
    k_mode2_node<<<dim3(1024 + M_ROWS / 2), dim3(256), 0, stream>>>(
        feat, WT, PREB, ssg_rel, ssg_obj, offs, lists, brel, bo, out0, out1);
}

// Round 7
// 221.023 us; speedup vs baseline: 1.4063x; 1.4063x over previous
//
#include <hip/hip_runtime.h>
#include <hip/hip_bf16.h>

typedef __attribute__((ext_vector_type(8))) short bf16x8;
typedef __attribute__((ext_vector_type(4))) float f32x4;

#define N_OBJ 1024
#define N_REL 1024
#define NB 32
#define D 512
#define VOCAB 2048
#define M_ROWS (NB * N_REL)          // 32768
#define PRE_BLK (VOCAB * D)          // 1048576 elems per PRE block (bf16)
#define WT_BLK (D * D)               // 262144 elems per transposed weight block

__device__ __forceinline__ ushort f2bf(float f) {
    union { float f; unsigned u; } v; v.f = f;
    unsigned u = v.u;
    unsigned r = (u + 0x7FFFu + ((u >> 16) & 1u)) >> 16;
    return (ushort)r;
}
__device__ __forceinline__ float bf2f(ushort h) {
    union { unsigned u; float f; } v; v.u = ((unsigned)h) << 16;
    return v.f;
}

// global -> LDS async 16B copy (m97 pattern; dest wave-uniform base + lane*16)
__device__ __forceinline__ void gload16(const ushort* g, const ushort* l) {
    __builtin_amdgcn_global_load_lds(
        (const __attribute__((address_space(1))) void*)(unsigned long long)(const void*)g,
        (__attribute__((address_space(3))) void*)(unsigned)(unsigned long long)(const void*)l,
        16, 0, 0);
}

// ================= GEMM body: 128x128 tile, BK=64, global_load_lds =================
// MODE 0: PREB[q] = EB @ WT[wtq[q]]      K=512, lda=512, bf16 out
// MODE 1: obj_f = sbjf @ Wobj0           K=512, lda=1024 -> featbuf hi
// MODE 2: rel_f = [sbjf|objf] @ [Wrel0;Wrel1]  K=1024 -> out0 + rel mask
template <int MODE>
__device__ __forceinline__ void gemm_body(
    int mt, int nt, int q, int tid,
    ushort* __restrict__ sA, ushort* __restrict__ sB,
    const ushort* __restrict__ A, const ushort* __restrict__ WT,
    ushort* __restrict__ PREB,
    const int* __restrict__ ssg_rel, const int* __restrict__ ssg_obj,
    const float* __restrict__ bias,
    ushort* __restrict__ featbuf, float* __restrict__ out0,
    float* __restrict__ out1) {
    const int m0 = mt * 128;
    constexpr int LDA = (MODE == 0) ? 512 : 1024;
    constexpr int KTOT = (MODE == 2) ? 1024 : 512;

    const ushort* BT0;
    const ushort* BT1 = nullptr;
    ushort* PREq = nullptr;
    if (MODE == 0) {
        const int wtq[9] = {0, 1, 2, 4, 5, 8, 9, 10, 11};
        BT0 = WT + (size_t)wtq[q] * WT_BLK + (size_t)nt * 128 * 512;
        PREq = PREB + (size_t)q * PRE_BLK;
    } else if (MODE == 1) {
        BT0 = WT + (size_t)3 * WT_BLK + (size_t)nt * 128 * 512;
    } else {
        BT0 = WT + (size_t)6 * WT_BLK + (size_t)nt * 128 * 512;
        BT1 = WT + (size_t)7 * WT_BLK + (size_t)nt * 128 * 512;
    }

    const int wave = tid >> 6;
    const int wm = wave >> 1, wn = wave & 1;
    const int lr = tid & 15, lk = (tid & 63) >> 4;

    f32x4 acc[4][4];
#pragma unroll
    for (int mi = 0; mi < 4; mi++)
#pragma unroll
        for (int ni = 0; ni < 4; ni++)
            acc[mi][ni] = (f32x4){0.f, 0.f, 0.f, 0.f};

    const ushort* Ag = A + (size_t)m0 * LDA;
    const int srow = tid >> 3;            // 0..31
    const int scol = (tid & 7) * 8;       // 0..56

    for (int k0 = 0; k0 < KTOT; k0 += 64) {
        const ushort* As = Ag + (size_t)srow * LDA + k0 + scol;
        const ushort* Bbase = (MODE == 2 && k0 >= 512) ? (BT1 + (k0 - 512)) : (BT0 + k0);
        const ushort* Bs = Bbase + (size_t)srow * 512 + scol;
#pragma unroll
        for (int i = 0; i < 4; i++)
            gload16(As + (size_t)i * 32 * LDA, &sA[i * 2048 + tid * 8]);
#pragma unroll
        for (int i = 0; i < 4; i++)
            gload16(Bs + (size_t)i * 32 * 512, &sB[i * 2048 + tid * 8]);
        __syncthreads();
#pragma unroll
        for (int ks = 0; ks < 2; ks++) {
            bf16x8 af[4], bfr[4];
#pragma unroll
            for (int mi = 0; mi < 4; mi++)
                af[mi] = *(const bf16x8*)&sA[(wm * 64 + mi * 16 + lr) * 64 + ks * 32 + lk * 8];
#pragma unroll
            for (int ni = 0; ni < 4; ni++)
                bfr[ni] = *(const bf16x8*)&sB[(wn * 64 + ni * 16 + lr) * 64 + ks * 32 + lk * 8];
#pragma unroll
            for (int mi = 0; mi < 4; mi++)
#pragma unroll
                for (int ni = 0; ni < 4; ni++)
                    acc[mi][ni] = __builtin_amdgcn_mfma_f32_16x16x32_bf16(af[mi], bfr[ni], acc[mi][ni], 0, 0, 0);
        }
        __syncthreads();
    }

    // ---- epilogue ----
    int* sIo  = (int*)sA;
    int* sRid = sIo + 128;
    if (MODE == 1 || MODE == 2) {
        if (tid < 128) {
            int R = m0 + tid;
            int rid = ssg_rel[R * 3 + 2];
            sRid[tid] = rid;
            if (MODE == 1) sIo[tid] = ssg_obj[(R & ~(N_OBJ - 1)) + ssg_rel[R * 3 + 1]];
            if (MODE == 2 && nt == 0) {
                int b = R >> 10, rr = R & (N_REL - 1);
                out1[(size_t)b * 3072 + 1024 + rr] = (rid == 1) ? 1.0f : 0.0f;
            }
        }
        __syncthreads();
    }

#pragma unroll
    for (int mi = 0; mi < 4; mi++) {
#pragma unroll
        for (int ni = 0; ni < 4; ni++) {
            int c = wn * 64 + ni * 16 + lr;
            int ch = nt * 128 + c;
#pragma unroll
            for (int j = 0; j < 4; j++) {
                int rl = wm * 64 + mi * 16 + lk * 4 + j;
                int R = m0 + rl;
                float v = acc[mi][ni][j];
                if (MODE == 0) {
                    PREq[(size_t)R * 512 + ch] = f2bf(v);
                } else if (MODE == 1) {
                    int rid = sRid[rl];
                    int io = sIo[rl];
                    float t = v + bf2f(PREB[(size_t)3 * PRE_BLK + (size_t)io * 512 + ch])
                                + bf2f(PREB[(size_t)4 * PRE_BLK + (size_t)rid * 512 + ch])
                                + bias[ch];
                    t = fmaxf(t, 0.f);
                    if (rid == 1) t = 0.f;
                    featbuf[(size_t)R * 1024 + 512 + ch] = f2bf(t);
                } else {  // MODE 2
                    int rid = sRid[rl];
                    float t = v + bf2f(PREB[(size_t)5 * PRE_BLK + (size_t)rid * 512 + ch])
                                + bias[ch];
                    t = fmaxf(t, 0.f);
                    if (rid == 1) t = 0.f;
                    int b = R >> 10, rr = R & (N_REL - 1);
                    out0[((size_t)(b * 3072 + 1024 + rr)) * 512 + ch] = t;
                }
            }
        }
    }
}

// ================= L1: cvt_emb + transpose_w + csr-zero (independent, tiny) ========
__global__ __launch_bounds__(256)
void k_setup(const float* __restrict__ E, ushort* __restrict__ EB,
             const float* __restrict__ Wsbj, const float* __restrict__ Wobj,
             const float* __restrict__ Wrel, const float* __restrict__ Wo,
             const float* __restrict__ Wa, ushort* __restrict__ WT,
             int* __restrict__ cnt) {
    int blk = blockIdx.x, tid = threadIdx.x;
    if (blk < 1024) {                       // cvt_emb over 262144 float4 groups
        int i = blk * 256 + tid;
        float4 v = ((const float4*)E)[i];
        ushort4 o; o.x = f2bf(v.x); o.y = f2bf(v.y); o.z = f2bf(v.z); o.w = f2bf(v.w);
        ((ushort4*)EB)[i] = o;
    } else if (blk < 4096) {                // transpose: 3072 blocks
        __shared__ float s[32][33];
        int bb = blk - 1024;
        int q = bb >> 8, rem = bb & 255;
        int bx = rem & 15, by = rem >> 4;
        const float* src; int ro;
        if (q < 3)       { src = Wsbj; ro = q * 512; }
        else if (q < 6)  { src = Wobj; ro = (q - 3) * 512; }
        else if (q < 9)  { src = Wrel; ro = (q - 6) * 512; }
        else if (q == 9) { src = Wo;   ro = 0; }
        else             { src = Wa;   ro = (q - 10) * 512; }
        int tx = tid & 31, ty = tid >> 5;    // 32 x 8
        int kbase = by * 32, nbase = bx * 32;
#pragma unroll
        for (int i = 0; i < 4; i++) {
            int k = kbase + ty + i * 8;
            s[ty + i * 8][tx] = src[(size_t)(ro + k) * 512 + nbase + tx];
        }
        __syncthreads();
        ushort* dst = WT + (size_t)q * WT_BLK;
#pragma unroll
        for (int i = 0; i < 4; i++) {
            int n = nbase + ty + i * 8;
            dst[(size_t)n * 512 + kbase + tx] = f2bf(s[tx][ty + i * 8]);
        }
    } else {                                // zero cnt: 128 blocks
        cnt[(blk - 4096) * 256 + tid] = 0;
    }
}

// ================= L2: CSR count =================
__global__ void k_csr_count(const int* __restrict__ ssg_rel, int* __restrict__ cnt) {
    int r = blockIdx.x * 256 + threadIdx.x;
    int bb = r & ~(N_OBJ - 1);
    atomicAdd(&cnt[bb + ssg_rel[r * 3 + 0]], 1);
    atomicAdd(&cnt[bb + ssg_rel[r * 3 + 1]], 1);
}

// ================= L3: CSR scan =================
__global__ __launch_bounds__(1024)
void k_csr_scan(const int* __restrict__ cnt, int* __restrict__ offs, int* __restrict__ cursor) {
    __shared__ int part[1024];
    int t = threadIdx.x;
    int base = t * 32;
    int local[32];
    int sum = 0;
#pragma unroll
    for (int i = 0; i < 32; i++) { local[i] = sum; sum += cnt[base + i]; }
    part[t] = sum;
    __syncthreads();
    for (int d = 1; d < 1024; d <<= 1) {
        int v = (t >= d) ? part[t - d] : 0;
        __syncthreads();
        part[t] += v;
        __syncthreads();
    }
    int excl = (t == 0) ? 0 : part[t - 1];
#pragma unroll
    for (int i = 0; i < 32; i++) {
        int o = excl + local[i];
        offs[base + i] = o;
        cursor[base + i] = o;
    }
    if (t == 1023) offs[32768] = part[1023];
}

// ================= L4: MODE0 GEMM (576 blocks, internal skip) + CSR fill ===========
__global__ __launch_bounds__(256)
void k_pre_fill(const ushort* __restrict__ EB, const ushort* __restrict__ WT,
                ushort* __restrict__ PREB, const int* __restrict__ ssg_rel,
                int* __restrict__ cursor, int* __restrict__ lists) {
    int blk = blockIdx.x, tid = threadIdx.x;
    if (blk < 576) {
        int q = blk >> 6, mt = (blk >> 2) & 15, nt = blk & 3;
        if ((q == 2 || q == 4 || q == 5) && mt >= 8) return;  // rid-indexed: rows<1024
        __shared__ __attribute__((aligned(16))) ushort sA[128 * 64];
        __shared__ __attribute__((aligned(16))) ushort sB[128 * 64];
        gemm_body<0>(mt, nt, q, tid, sA, sB, EB, WT, PREB,
                     nullptr, nullptr, nullptr, nullptr, nullptr, nullptr);
    } else {
        int r = (blk - 576) * 256 + tid;
        int bb = r & ~(N_OBJ - 1);
        int p0 = atomicAdd(&cursor[bb + ssg_rel[r * 3 + 0]], 1);
        lists[p0] = r * 2;
        int p1 = atomicAdd(&cursor[bb + ssg_rel[r * 3 + 1]], 1);
        lists[p1] = r * 2 + 1;
    }
}

// ================= L5: sbj_f lookup layer (standalone, 0 LDS) =================
__global__ void k_sbj(const int* __restrict__ ssg_rel, const int* __restrict__ ssg_obj,
                      const ushort* __restrict__ PREB, const float* __restrict__ b_sbj,
                      ushort* __restrict__ featbuf) {
    int R = blockIdx.x * 2 + (threadIdx.x >> 7);
    int c4 = threadIdx.x & 127;
    int sid = ssg_rel[R * 3 + 0];
    int oid = ssg_rel[R * 3 + 1];
    int rid = ssg_rel[R * 3 + 2];
    int bb = R & ~(N_OBJ - 1);
    int is_ = ssg_obj[bb + sid];
    int io  = ssg_obj[bb + oid];
    ushort4 p1 = ((const ushort4*)(PREB + (size_t)is_ * 512))[c4];
    ushort4 p2 = ((const ushort4*)(PREB + (size_t)1 * PRE_BLK + (size_t)io * 512))[c4];
    ushort4 p3 = ((const ushort4*)(PREB + (size_t)2 * PRE_BLK + (size_t)rid * 512))[c4];
    float4 b  = ((const float4*)b_sbj)[c4];
    float4 v;
    v.x = fmaxf(bf2f(p1.x) + bf2f(p2.x) + bf2f(p3.x) + b.x, 0.f);
    v.y = fmaxf(bf2f(p1.y) + bf2f(p2.y) + bf2f(p3.y) + b.y, 0.f);
    v.z = fmaxf(bf2f(p1.z) + bf2f(p2.z) + bf2f(p3.z) + b.z, 0.f);
    v.w = fmaxf(bf2f(p1.w) + bf2f(p2.w) + bf2f(p3.w) + b.w, 0.f);
    if (rid == 1) { v.x = v.y = v.z = v.w = 0.f; }
    ushort4 o; o.x = f2bf(v.x); o.y = f2bf(v.y); o.z = f2bf(v.z); o.w = f2bf(v.w);
    *(ushort4*)&featbuf[(size_t)R * 1024 + c4 * 4] = o;
}

// ================= L6: MODE1 GEMM (standalone) =================
__global__ __launch_bounds__(256)
void k_gemm1(const ushort* __restrict__ feat, const ushort* __restrict__ WT,
             ushort* __restrict__ PREB,
             const int* __restrict__ ssg_rel, const int* __restrict__ ssg_obj,
             const float* __restrict__ b_obj, ushort* __restrict__ featbuf) {
    int blk = blockIdx.x;
    int nb = (blk & 7) * 128 + (blk >> 3);   // XCD-chunked swizzle (1024 % 8 == 0)
    int mt = nb >> 2, nt = nb & 3;
    __shared__ __attribute__((aligned(16))) ushort sA[128 * 64];
    __shared__ __attribute__((aligned(16))) ushort sB[128 * 64];
    gemm_body<1>(mt, nt, 0, threadIdx.x, sA, sB, feat, WT, PREB,
                 ssg_rel, ssg_obj, b_obj, featbuf, nullptr, nullptr);
}

// ================= L7: MODE2 GEMM (standalone) =================
__global__ __launch_bounds__(256)
void k_gemm2(const ushort* __restrict__ feat, const ushort* __restrict__ WT,
             ushort* __restrict__ PREB,
             const int* __restrict__ ssg_rel, const int* __restrict__ ssg_obj,
             const float* __restrict__ b_rel,
             float* __restrict__ out0, float* __restrict__ out1) {
    int blk = blockIdx.x;
    int nb = (blk & 7) * 128 + (blk >> 3);
    int mt = nb >> 2, nt = nb & 3;
    __shared__ __attribute__((aligned(16))) ushort sA[128 * 64];
    __shared__ __attribute__((aligned(16))) ushort sB[128 * 64];
    gemm_body<2>(mt, nt, 0, threadIdx.x, sA, sB, feat, WT, PREB,
                 ssg_rel, ssg_obj, b_rel, nullptr, out0, out1);
}

// ================= L8: fused per-object pass: node gather + att + masks (0 LDS) ====
__global__ void k_objpass(const int* __restrict__ ssg_obj, const int* __restrict__ ssg_att,
                          const int* __restrict__ offs, const int* __restrict__ lists,
                          const ushort* __restrict__ feat, const ushort* __restrict__ PREB,
                          const float* __restrict__ b_o, const float* __restrict__ b_a,
                          float* __restrict__ out0, float* __restrict__ out1) {
    int Ro = blockIdx.x * 2 + (threadIdx.x >> 7);   // b*1024 + o
    int c4 = threadIdx.x & 127;                     // 4 channels each
    int iv = ssg_obj[Ro];
    int bq = Ro >> 10, o = Ro & (N_OBJ - 1);

    // --- node: init + CSR gather, /2048 ---
    float4 bo4 = ((const float4*)b_o)[c4];
    ushort4 q6 = ((const ushort4*)(PREB + (size_t)6 * PRE_BLK + (size_t)iv * 512))[c4];
    float a0 = 0.f, a1 = 0.f, a2 = 0.f, a3 = 0.f;
    if (iv != 1) {
        a0 = fmaxf(bf2f(q6.x) + bo4.x, 0.f);
        a1 = fmaxf(bf2f(q6.y) + bo4.y, 0.f);
        a2 = fmaxf(bf2f(q6.z) + bo4.z, 0.f);
        a3 = fmaxf(bf2f(q6.w) + bo4.w, 0.f);
    }
    int s = offs[Ro], e = offs[Ro + 1];
    for (int i = s; i < e; ++i) {
        int ent = lists[i];
        ushort4 u = ((const ushort4*)(feat + (size_t)(ent >> 1) * 1024 + (ent & 1) * 512))[c4];
        a0 += bf2f(u.x); a1 += bf2f(u.y); a2 += bf2f(u.z); a3 += bf2f(u.w);
    }
    float4 r;
    r.x = a0 * (1.0f / 2048.0f); r.y = a1 * (1.0f / 2048.0f);
    r.z = a2 * (1.0f / 2048.0f); r.w = a3 * (1.0f / 2048.0f);
    ((float4*)out0)[((size_t)(bq * 3072 + o)) * 128 + c4] = r;

    // --- att features ---
    int j0 = ssg_att[Ro * 4 + 0], j1 = ssg_att[Ro * 4 + 1];
    int j2 = ssg_att[Ro * 4 + 2], j3 = ssg_att[Ro * 4 + 3];
    float4 ba4 = ((const float4*)b_a)[c4];
    ushort4 q7 = ((const ushort4*)(PREB + (size_t)7 * PRE_BLK + (size_t)iv * 512))[c4];
    float bx = bf2f(q7.x) + ba4.x, by = bf2f(q7.y) + ba4.y;
    float bz = bf2f(q7.z) + ba4.z, bw = bf2f(q7.w) + ba4.w;
    int cnt = (j0 != 1) + (j1 != 1) + (j2 != 1) + (j3 != 1);
    float inv = cnt ? 1.0f / (float)cnt : 0.f;
    float sx = 0.f, sy = 0.f, sz = 0.f, sw = 0.f;
    const ushort* A2 = PREB + (size_t)8 * PRE_BLK;
#define ACC_ATT(J) if ((J) != 1) { \
        ushort4 a2 = ((const ushort4*)(A2 + (size_t)(J) * 512))[c4]; \
        sx += fmaxf(bx + bf2f(a2.x), 0.f); sy += fmaxf(by + bf2f(a2.y), 0.f); \
        sz += fmaxf(bz + bf2f(a2.z), 0.f); sw += fmaxf(bw + bf2f(a2.w), 0.f); }
    ACC_ATT(j0) ACC_ATT(j1) ACC_ATT(j2) ACC_ATT(j3)
#undef ACC_ATT
    float4 sv; sv.x = sx * inv; sv.y = sy * inv; sv.z = sz * inv; sv.w = sw * inv;
    ((float4*)out0)[((size_t)(bq * 3072 + 2048 + o)) * 128 + c4] = sv;

    // --- masks (obj + att sections) ---
    if (c4 == 0) {
        out1[(size_t)bq * 3072 + o] = (iv == 1) ? 1.0f : 0.0f;
        out1[(size_t)bq * 3072 + 2048 + o] = (cnt == 0) ? 1.0f : 0.0f;
    }
}

extern "C" void kernel_launch(void* const* d_in, const int* in_sizes, int n_in,
                              void* d_out, int out_size, void* d_ws, size_t ws_size,
                              hipStream_t stream) {
    const int*   ssg_rel = (const int*)d_in[0];
    const int*   ssg_obj = (const int*)d_in[1];
    const int*   ssg_att = (const int*)d_in[2];
    const float* emb     = (const float*)d_in[3];
    const float* Wsbj    = (const float*)d_in[4];
    const float* bsbj    = (const float*)d_in[5];
    const float* Wobj    = (const float*)d_in[6];
    const float* bobj    = (const float*)d_in[7];
    const float* Wrel    = (const float*)d_in[8];
    const float* brel    = (const float*)d_in[9];
    const float* Wo      = (const float*)d_in[10];
    const float* bo      = (const float*)d_in[11];
    const float* Wa      = (const float*)d_in[12];
    const float* ba      = (const float*)d_in[13];

    float* out0 = (float*)d_out;
    float* out1 = out0 + (size_t)NB * 3072 * 512;

    char* w = (char*)d_ws;
    ushort* EB     = (ushort*)w; w += (size_t)VOCAB * D * 2;          //  2.0 MB
    ushort* WT     = (ushort*)w; w += (size_t)12 * WT_BLK * 2;        //  6.3 MB
    ushort* PREB   = (ushort*)w; w += (size_t)9 * PRE_BLK * 2;        // 18.9 MB (bf16)
    ushort* feat   = (ushort*)w; w += (size_t)M_ROWS * 1024 * 2;      // 67.1 MB  [sbjf | objf]
    int*    cnt    = (int*)   w; w += (size_t)32768 * 4;
    int*    offs   = (int*)   w; w += (size_t)32769 * 4;
    int*    cursor = (int*)   w; w += (size_t)32768 * 4;
    int*    lists  = (int*)   w; w += (size_t)65536 * 4;

    // L1: emb cvt + weight transpose + csr zero (independent)
    k_setup<<<dim3(4224), dim3(256), 0, stream>>>(emb, EB, Wsbj, Wobj, Wrel, Wo, Wa, WT, cnt);
    // L2: csr count
    k_csr_count<<<dim3(128), dim3(256), 0, stream>>>(ssg_rel, cnt);
    // L3: csr scan
    k_csr_scan<<<dim3(1), dim3(1024), 0, stream>>>(cnt, offs, cursor);
    // L4: PREB = E @ {9 blocks} (bf16)  ||  csr fill
    k_pre_fill<<<dim3(704), dim3(256), 0, stream>>>(EB, WT, PREB, ssg_rel, cursor, lists);
    // L5: sbj_f lookup layer -> feat lo
    k_sbj<<<dim3(M_ROWS / 2), dim3(256), 0, stream>>>(ssg_rel, ssg_obj, PREB, bsbj, feat);
    // L6: obj_f GEMM -> feat hi
    k_gemm1<<<dim3(1024), dim3(256), 0, stream>>>(feat, WT, PREB, ssg_rel, ssg_obj, bobj, feat);
    // L7: rel_f GEMM -> out0 + rel mask
    k_gemm2<<<dim3(1024), dim3(256), 0, stream>>>(feat, WT, PREB, ssg_rel, ssg_obj, brel, out0, out1);
    // L8: per-object pass: node gather + att + obj/att masks
    k_objpass<<<dim3(M_ROWS / 2), dim3(256), 0, stream>>>(ssg_obj, ssg_att, offs, lists,
                                                          feat, PREB, bo, ba, out0, out1);
}

// Round 8
// 202.371 us; speedup vs baseline: 1.5359x; 1.0922x over previous
//
#include <hip/hip_runtime.h>
#include <hip/hip_bf16.h>

typedef __attribute__((ext_vector_type(8))) short bf16x8;
typedef __attribute__((ext_vector_type(4))) float f32x4;

#define N_OBJ 1024
#define N_REL 1024
#define NB 32
#define D 512
#define VOCAB 2048
#define M_ROWS (NB * N_REL)          // 32768
#define PRE_BLK (VOCAB * D)          // 1048576 elems per PRE block (bf16)
#define WT_BLK (D * D)               // 262144 elems per transposed weight block

__device__ __forceinline__ ushort f2bf(float f) {
    union { float f; unsigned u; } v; v.f = f;
    unsigned u = v.u;
    unsigned r = (u + 0x7FFFu + ((u >> 16) & 1u)) >> 16;
    return (ushort)r;
}
__device__ __forceinline__ float bf2f(ushort h) {
    union { unsigned u; float f; } v; v.u = ((unsigned)h) << 16;
    return v.f;
}

// global -> LDS async 16B copy (dest wave-uniform base + lane*16)
__device__ __forceinline__ void gload16(const ushort* g, const ushort* l) {
    __builtin_amdgcn_global_load_lds(
        (const __attribute__((address_space(1))) void*)(unsigned long long)(const void*)g,
        (__attribute__((address_space(3))) void*)(unsigned)(unsigned long long)(const void*)l,
        16, 0, 0);
}
__device__ __forceinline__ unsigned lds_off(const void* p) {
    return (unsigned)(unsigned long long)(const __attribute__((address_space(3))) void*)p;
}
__device__ __forceinline__ bf16x8 ds_read128(unsigned off) {
    bf16x8 r;
    asm volatile("ds_read_b128 %0, %1" : "=v"(r) : "v"(off));
    return r;
}

// ================= old GEMM body (kept for MODE 0 only): 128x128, BK=64 ============
__device__ __forceinline__ void gemm0_body(
    int mt, int nt, int q, int tid,
    ushort* __restrict__ sA, ushort* __restrict__ sB,
    const ushort* __restrict__ A, const ushort* __restrict__ WT,
    ushort* __restrict__ PREB) {
    const int m0 = mt * 128;
    const int wtq[9] = {0, 1, 2, 4, 5, 8, 9, 10, 11};
    const ushort* BT0 = WT + (size_t)wtq[q] * WT_BLK + (size_t)nt * 128 * 512;
    ushort* PREq = PREB + (size_t)q * PRE_BLK;

    const int wave = tid >> 6;
    const int wm = wave >> 1, wn = wave & 1;
    const int lr = tid & 15, lk = (tid & 63) >> 4;

    f32x4 acc[4][4];
#pragma unroll
    for (int mi = 0; mi < 4; mi++)
#pragma unroll
        for (int ni = 0; ni < 4; ni++)
            acc[mi][ni] = (f32x4){0.f, 0.f, 0.f, 0.f};

    const ushort* Ag = A + (size_t)m0 * 512;
    const int srow = tid >> 3;            // 0..31
    const int scol = (tid & 7) * 8;       // 0..56

    for (int k0 = 0; k0 < 512; k0 += 64) {
        const ushort* As = Ag + (size_t)srow * 512 + k0 + scol;
        const ushort* Bs = BT0 + (size_t)srow * 512 + k0 + scol;
#pragma unroll
        for (int i = 0; i < 4; i++)
            gload16(As + (size_t)i * 32 * 512, &sA[i * 2048 + tid * 8]);
#pragma unroll
        for (int i = 0; i < 4; i++)
            gload16(Bs + (size_t)i * 32 * 512, &sB[i * 2048 + tid * 8]);
        __syncthreads();
#pragma unroll
        for (int ks = 0; ks < 2; ks++) {
            bf16x8 af[4], bfr[4];
#pragma unroll
            for (int mi = 0; mi < 4; mi++)
                af[mi] = *(const bf16x8*)&sA[(wm * 64 + mi * 16 + lr) * 64 + ks * 32 + lk * 8];
#pragma unroll
            for (int ni = 0; ni < 4; ni++)
                bfr[ni] = *(const bf16x8*)&sB[(wn * 64 + ni * 16 + lr) * 64 + ks * 32 + lk * 8];
#pragma unroll
            for (int mi = 0; mi < 4; mi++)
#pragma unroll
                for (int ni = 0; ni < 4; ni++)
                    acc[mi][ni] = __builtin_amdgcn_mfma_f32_16x16x32_bf16(af[mi], bfr[ni], acc[mi][ni], 0, 0, 0);
        }
        __syncthreads();
    }
#pragma unroll
    for (int mi = 0; mi < 4; mi++)
#pragma unroll
        for (int ni = 0; ni < 4; ni++) {
            int ch = nt * 128 + wn * 64 + ni * 16 + lr;
#pragma unroll
            for (int j = 0; j < 4; j++) {
                int R = m0 + wm * 64 + mi * 16 + lk * 4 + j;
                PREq[(size_t)R * 512 + ch] = f2bf(acc[mi][ni][j]);
            }
        }
}

// ================= NEW: 256x256 tile, BK=32, quad-buffer, counted vmcnt ============
// MODE 1: obj_f = sbjf @ Wobj0, K=512  -> featbuf hi (+PREB gathers)
// MODE 2: rel_f = [sbjf|objf] @ [Wrel0;Wrel1], K=1024 -> out0 (f32) + rel mask
template <int MODE>
__global__ __launch_bounds__(512, 2)
void k_gemm8(const ushort* __restrict__ A, const ushort* __restrict__ WT,
             const ushort* __restrict__ PREB,
             const int* __restrict__ ssg_rel, const int* __restrict__ ssg_obj,
             const float* __restrict__ bias,
             ushort* __restrict__ featbuf, float* __restrict__ out0,
             float* __restrict__ out1) {
    constexpr int KTOT = (MODE == 2) ? 1024 : 512;
    constexpr int NK = KTOT / 32;
    constexpr int LDA = 1024;
    // 4 buffers x {A,B} x 256 rows x 32 cols bf16 = 128 KiB
    __shared__ __attribute__((aligned(16))) ushort lds[4 * 2 * 256 * 32];

    const int tid = threadIdx.x;
    // XCD-aware: blocks with blockIdx%8==x land on XCD x; give each XCD a contiguous
    // mt range so the nt-pair sharing an A panel stays on one XCD's L2.
    int x = blockIdx.x & 7, jj = blockIdx.x >> 3;     // grid = 256 (=128 mt x 2 nt)
    const int mt = x * 16 + (jj >> 1), nt = jj & 1;
    const int m0 = mt * 256, n0 = nt * 256;

    const ushort* BT0 = WT + (size_t)((MODE == 1) ? 3 : 6) * WT_BLK + (size_t)n0 * 512;
    const ushort* BT1 = (MODE == 2) ? (WT + (size_t)7 * WT_BLK + (size_t)n0 * 512) : nullptr;

    const ushort* Ag = A + (size_t)m0 * LDA;
    const int srow = tid >> 2;            // 0..127
    const int scol = (tid & 3) * 8;       // elem col 0,8,16,24

    const int wave = tid >> 6, lane = tid & 63;
    const int wm = wave >> 2, wn = wave & 3;          // 2 x 4 waves
    const int lr = lane & 15, lk = lane >> 4;

    f32x4 acc[8][4];
#pragma unroll
    for (int mi = 0; mi < 8; mi++)
#pragma unroll
        for (int ni = 0; ni < 4; ni++)
            acc[mi][ni] = (f32x4){0.f, 0.f, 0.f, 0.f};

    // ---- staging: one K-tile (A 256x32 + B 256x32) = 4 gload16/thread ----
#define STAGE(KT) do {                                                          \
        int _b = (KT) & 3;                                                      \
        ushort* _dA = &lds[(_b * 2 + 0) * 8192];                                \
        ushort* _dB = &lds[(_b * 2 + 1) * 8192];                                \
        int _k0 = (KT) * 32;                                                    \
        const ushort* _Bb = (MODE == 2 && _k0 >= 512) ? (BT1 + (_k0 - 512))     \
                                                      : (BT0 + _k0);            \
        gload16(Ag + (size_t)(srow) * LDA + _k0 + scol, _dA + srow * 32 + scol);        \
        gload16(Ag + (size_t)(srow + 128) * LDA + _k0 + scol, _dA + (srow + 128) * 32 + scol); \
        gload16(_Bb + (size_t)(srow) * 512 + scol, _dB + srow * 32 + scol);             \
        gload16(_Bb + (size_t)(srow + 128) * 512 + scol, _dB + (srow + 128) * 32 + scol); \
    } while (0)

    // prologue: prefetch K-tiles 0..2 (12 loads in flight)
    STAGE(0); STAGE(1); STAGE(2);

    for (int kt = 0; kt < NK; ++kt) {
        // wait until K-tile kt's 4 loads are complete (leave younger ones in flight),
        // then barrier: kt's data visible to all waves AND all waves are done
        // reading buf[(kt+3)&3] (== buf[(kt-1)&3], consumed last iteration).
        if (kt + 3 < NK) {
            asm volatile("s_waitcnt vmcnt(8)\n\ts_barrier" ::: "memory");
            STAGE(kt + 3);
        } else if (kt + 3 == NK) {
            asm volatile("s_waitcnt vmcnt(8)\n\ts_barrier" ::: "memory");
        } else if (kt + 2 == NK) {
            asm volatile("s_waitcnt vmcnt(4)\n\ts_barrier" ::: "memory");
        } else {
            asm volatile("s_waitcnt vmcnt(0)\n\ts_barrier" ::: "memory");
        }
        // ---- compute K-tile kt ----
        {
            int buf = kt & 3;
            unsigned baseA = lds_off(&lds[(buf * 2 + 0) * 8192]) + (unsigned)(wm * 128) * 64 + lk * 16;
            unsigned baseB = lds_off(&lds[(buf * 2 + 1) * 8192]) + (unsigned)(wn * 64) * 64 + lk * 16;
            bf16x8 bfr[4], af[8];
#pragma unroll
            for (int ni = 0; ni < 4; ni++)
                bfr[ni] = ds_read128(baseB + (unsigned)(ni * 16 + lr) * 64);
#pragma unroll
            for (int mi = 0; mi < 8; mi++)
                af[mi] = ds_read128(baseA + (unsigned)(mi * 16 + lr) * 64);
            asm volatile("s_waitcnt lgkmcnt(0)" ::: "memory");
            __builtin_amdgcn_sched_barrier(0);
            __builtin_amdgcn_s_setprio(1);
#pragma unroll
            for (int mi = 0; mi < 8; mi++)
#pragma unroll
                for (int ni = 0; ni < 4; ni++)
                    acc[mi][ni] = __builtin_amdgcn_mfma_f32_16x16x32_bf16(af[mi], bfr[ni], acc[mi][ni], 0, 0, 0);
            __builtin_amdgcn_s_setprio(0);
        }
    }
#undef STAGE

    // ---- epilogue ----
    __syncthreads();
    int* sIo  = (int*)lds;            // overlay: 256 + 256 ints
    int* sRid = sIo + 256;
    if (tid < 256) {
        int R = m0 + tid;
        int rid = ssg_rel[R * 3 + 2];
        sRid[tid] = rid;
        if (MODE == 1) sIo[tid] = ssg_obj[(R & ~(N_OBJ - 1)) + ssg_rel[R * 3 + 1]];
        if (MODE == 2 && nt == 0) {
            int b = R >> 10, rr = R & (N_REL - 1);
            out1[(size_t)b * 3072 + 1024 + rr] = (rid == 1) ? 1.0f : 0.0f;
        }
    }
    __syncthreads();

#pragma unroll
    for (int mi = 0; mi < 8; mi++) {
#pragma unroll
        for (int ni = 0; ni < 4; ni++) {
            int ch = n0 + wn * 64 + ni * 16 + lr;
#pragma unroll
            for (int j = 0; j < 4; j++) {
                int rl = wm * 128 + mi * 16 + lk * 4 + j;
                int R = m0 + rl;
                float v = acc[mi][ni][j];
                if (MODE == 1) {
                    int rid = sRid[rl];
                    int io = sIo[rl];
                    float t = v + bf2f(PREB[(size_t)3 * PRE_BLK + (size_t)io * 512 + ch])
                                + bf2f(PREB[(size_t)4 * PRE_BLK + (size_t)rid * 512 + ch])
                                + bias[ch];
                    t = fmaxf(t, 0.f);
                    if (rid == 1) t = 0.f;
                    featbuf[(size_t)R * 1024 + 512 + ch] = f2bf(t);
                } else {
                    int rid = sRid[rl];
                    float t = v + bf2f(PREB[(size_t)5 * PRE_BLK + (size_t)rid * 512 + ch])
                                + bias[ch];
                    t = fmaxf(t, 0.f);
                    if (rid == 1) t = 0.f;
                    int b = R >> 10, rr = R & (N_REL - 1);
                    out0[((size_t)(b * 3072 + 1024 + rr)) * 512 + ch] = t;
                }
            }
        }
    }
}

// ================= L1: cvt_emb + transpose_w + csr-zero =================
__global__ __launch_bounds__(256)
void k_setup(const float* __restrict__ E, ushort* __restrict__ EB,
             const float* __restrict__ Wsbj, const float* __restrict__ Wobj,
             const float* __restrict__ Wrel, const float* __restrict__ Wo,
             const float* __restrict__ Wa, ushort* __restrict__ WT,
             int* __restrict__ cnt) {
    int blk = blockIdx.x, tid = threadIdx.x;
    if (blk < 1024) {
        int i = blk * 256 + tid;
        float4 v = ((const float4*)E)[i];
        ushort4 o; o.x = f2bf(v.x); o.y = f2bf(v.y); o.z = f2bf(v.z); o.w = f2bf(v.w);
        ((ushort4*)EB)[i] = o;
    } else if (blk < 4096) {
        __shared__ float s[32][33];
        int bb = blk - 1024;
        int q = bb >> 8, rem = bb & 255;
        int bx = rem & 15, by = rem >> 4;
        const float* src; int ro;
        if (q < 3)       { src = Wsbj; ro = q * 512; }
        else if (q < 6)  { src = Wobj; ro = (q - 3) * 512; }
        else if (q < 9)  { src = Wrel; ro = (q - 6) * 512; }
        else if (q == 9) { src = Wo;   ro = 0; }
        else             { src = Wa;   ro = (q - 10) * 512; }
        int tx = tid & 31, ty = tid >> 5;
        int kbase = by * 32, nbase = bx * 32;
#pragma unroll
        for (int i = 0; i < 4; i++) {
            int k = kbase + ty + i * 8;
            s[ty + i * 8][tx] = src[(size_t)(ro + k) * 512 + nbase + tx];
        }
        __syncthreads();
        ushort* dst = WT + (size_t)q * WT_BLK;
#pragma unroll
        for (int i = 0; i < 4; i++) {
            int n = nbase + ty + i * 8;
            dst[(size_t)n * 512 + kbase + tx] = f2bf(s[tx][ty + i * 8]);
        }
    } else {
        cnt[(blk - 4096) * 256 + tid] = 0;
    }
}

// ================= L2: CSR count =================
__global__ void k_csr_count(const int* __restrict__ ssg_rel, int* __restrict__ cnt) {
    int r = blockIdx.x * 256 + threadIdx.x;
    int bb = r & ~(N_OBJ - 1);
    atomicAdd(&cnt[bb + ssg_rel[r * 3 + 0]], 1);
    atomicAdd(&cnt[bb + ssg_rel[r * 3 + 1]], 1);
}

// ================= L3: CSR scan =================
__global__ __launch_bounds__(1024)
void k_csr_scan(const int* __restrict__ cnt, int* __restrict__ offs, int* __restrict__ cursor) {
    __shared__ int part[1024];
    int t = threadIdx.x;
    int base = t * 32;
    int local[32];
    int sum = 0;
#pragma unroll
    for (int i = 0; i < 32; i++) { local[i] = sum; sum += cnt[base + i]; }
    part[t] = sum;
    __syncthreads();
    for (int d = 1; d < 1024; d <<= 1) {
        int v = (t >= d) ? part[t - d] : 0;
        __syncthreads();
        part[t] += v;
        __syncthreads();
    }
    int excl = (t == 0) ? 0 : part[t - 1];
#pragma unroll
    for (int i = 0; i < 32; i++) {
        int o = excl + local[i];
        offs[base + i] = o;
        cursor[base + i] = o;
    }
    if (t == 1023) offs[32768] = part[1023];
}

// ================= L4: MODE0 GEMM (576 blocks, skip) + CSR fill =================
__global__ __launch_bounds__(256)
void k_pre_fill(const ushort* __restrict__ EB, const ushort* __restrict__ WT,
                ushort* __restrict__ PREB, const int* __restrict__ ssg_rel,
                int* __restrict__ cursor, int* __restrict__ lists) {
    int blk = blockIdx.x, tid = threadIdx.x;
    if (blk < 576) {
        int q = blk >> 6, mt = (blk >> 2) & 15, nt = blk & 3;
        if ((q == 2 || q == 4 || q == 5) && mt >= 8) return;
        __shared__ __attribute__((aligned(16))) ushort sA[128 * 64];
        __shared__ __attribute__((aligned(16))) ushort sB[128 * 64];
        gemm0_body(mt, nt, q, tid, sA, sB, EB, WT, PREB);
    } else {
        int r = (blk - 576) * 256 + tid;
        int bb = r & ~(N_OBJ - 1);
        int p0 = atomicAdd(&cursor[bb + ssg_rel[r * 3 + 0]], 1);
        lists[p0] = r * 2;
        int p1 = atomicAdd(&cursor[bb + ssg_rel[r * 3 + 1]], 1);
        lists[p1] = r * 2 + 1;
    }
}

// ================= L5: sbj_f lookup layer =================
__global__ void k_sbj(const int* __restrict__ ssg_rel, const int* __restrict__ ssg_obj,
                      const ushort* __restrict__ PREB, const float* __restrict__ b_sbj,
                      ushort* __restrict__ featbuf) {
    int R = blockIdx.x * 2 + (threadIdx.x >> 7);
    int c4 = threadIdx.x & 127;
    int sid = ssg_rel[R * 3 + 0];
    int oid = ssg_rel[R * 3 + 1];
    int rid = ssg_rel[R * 3 + 2];
    int bb = R & ~(N_OBJ - 1);
    int is_ = ssg_obj[bb + sid];
    int io  = ssg_obj[bb + oid];
    ushort4 p1 = ((const ushort4*)(PREB + (size_t)is_ * 512))[c4];
    ushort4 p2 = ((const ushort4*)(PREB + (size_t)1 * PRE_BLK + (size_t)io * 512))[c4];
    ushort4 p3 = ((const ushort4*)(PREB + (size_t)2 * PRE_BLK + (size_t)rid * 512))[c4];
    float4 b  = ((const float4*)b_sbj)[c4];
    float4 v;
    v.x = fmaxf(bf2f(p1.x) + bf2f(p2.x) + bf2f(p3.x) + b.x, 0.f);
    v.y = fmaxf(bf2f(p1.y) + bf2f(p2.y) + bf2f(p3.y) + b.y, 0.f);
    v.z = fmaxf(bf2f(p1.z) + bf2f(p2.z) + bf2f(p3.z) + b.z, 0.f);
    v.w = fmaxf(bf2f(p1.w) + bf2f(p2.w) + bf2f(p3.w) + b.w, 0.f);
    if (rid == 1) { v.x = v.y = v.z = v.w = 0.f; }
    ushort4 o; o.x = f2bf(v.x); o.y = f2bf(v.y); o.z = f2bf(v.z); o.w = f2bf(v.w);
    *(ushort4*)&featbuf[(size_t)R * 1024 + c4 * 4] = o;
}

// ================= L8: per-object pass: node gather + att + masks =================
__global__ void k_objpass(const int* __restrict__ ssg_obj, const int* __restrict__ ssg_att,
                          const int* __restrict__ offs, const int* __restrict__ lists,
                          const ushort* __restrict__ feat, const ushort* __restrict__ PREB,
                          const float* __restrict__ b_o, const float* __restrict__ b_a,
                          float* __restrict__ out0, float* __restrict__ out1) {
    int Ro = blockIdx.x * 2 + (threadIdx.x >> 7);
    int c4 = threadIdx.x & 127;
    int iv = ssg_obj[Ro];
    int bq = Ro >> 10, o = Ro & (N_OBJ - 1);

    float4 bo4 = ((const float4*)b_o)[c4];
    ushort4 q6 = ((const ushort4*)(PREB + (size_t)6 * PRE_BLK + (size_t)iv * 512))[c4];
    float a0 = 0.f, a1 = 0.f, a2 = 0.f, a3 = 0.f;
    if (iv != 1) {
        a0 = fmaxf(bf2f(q6.x) + bo4.x, 0.f);
        a1 = fmaxf(bf2f(q6.y) + bo4.y, 0.f);
        a2 = fmaxf(bf2f(q6.z) + bo4.z, 0.f);
        a3 = fmaxf(bf2f(q6.w) + bo4.w, 0.f);
    }
    int s = offs[Ro], e = offs[Ro + 1];
    for (int i = s; i < e; ++i) {
        int ent = lists[i];
        ushort4 u = ((const ushort4*)(feat + (size_t)(ent >> 1) * 1024 + (ent & 1) * 512))[c4];
        a0 += bf2f(u.x); a1 += bf2f(u.y); a2 += bf2f(u.z); a3 += bf2f(u.w);
    }
    float4 r;
    r.x = a0 * (1.0f / 2048.0f); r.y = a1 * (1.0f / 2048.0f);
    r.z = a2 * (1.0f / 2048.0f); r.w = a3 * (1.0f / 2048.0f);
    ((float4*)out0)[((size_t)(bq * 3072 + o)) * 128 + c4] = r;

    int j0 = ssg_att[Ro * 4 + 0], j1 = ssg_att[Ro * 4 + 1];
    int j2 = ssg_att[Ro * 4 + 2], j3 = ssg_att[Ro * 4 + 3];
    float4 ba4 = ((const float4*)b_a)[c4];
    ushort4 q7 = ((const ushort4*)(PREB + (size_t)7 * PRE_BLK + (size_t)iv * 512))[c4];
    float bx = bf2f(q7.x) + ba4.x, by = bf2f(q7.y) + ba4.y;
    float bz = bf2f(q7.z) + ba4.z, bw = bf2f(q7.w) + ba4.w;
    int cnt = (j0 != 1) + (j1 != 1) + (j2 != 1) + (j3 != 1);
    float inv = cnt ? 1.0f / (float)cnt : 0.f;
    float sx = 0.f, sy = 0.f, sz = 0.f, sw = 0.f;
    const ushort* A2 = PREB + (size_t)8 * PRE_BLK;
#define ACC_ATT(J) if ((J) != 1) { \
        ushort4 a2 = ((const ushort4*)(A2 + (size_t)(J) * 512))[c4]; \
        sx += fmaxf(bx + bf2f(a2.x), 0.f); sy += fmaxf(by + bf2f(a2.y), 0.f); \
        sz += fmaxf(bz + bf2f(a2.z), 0.f); sw += fmaxf(bw + bf2f(a2.w), 0.f); }
    ACC_ATT(j0) ACC_ATT(j1) ACC_ATT(j2) ACC_ATT(j3)
#undef ACC_ATT
    float4 sv; sv.x = sx * inv; sv.y = sy * inv; sv.z = sz * inv; sv.w = sw * inv;
    ((float4*)out0)[((size_t)(bq * 3072 + 2048 + o)) * 128 + c4] = sv;

    if (c4 == 0) {
        out1[(size_t)bq * 3072 + o] = (iv == 1) ? 1.0f : 0.0f;
        out1[(size_t)bq * 3072 + 2048 + o] = (cnt == 0) ? 1.0f : 0.0f;
    }
}

extern "C" void kernel_launch(void* const* d_in, const int* in_sizes, int n_in,
                              void* d_out, int out_size, void* d_ws, size_t ws_size,
                              hipStream_t stream) {
    const int*   ssg_rel = (const int*)d_in[0];
    const int*   ssg_obj = (const int*)d_in[1];
    const int*   ssg_att = (const int*)d_in[2];
    const float* emb     = (const float*)d_in[3];
    const float* Wsbj    = (const float*)d_in[4];
    const float* bsbj    = (const float*)d_in[5];
    const float* Wobj    = (const float*)d_in[6];
    const float* bobj    = (const float*)d_in[7];
    const float* Wrel    = (const float*)d_in[8];
    const float* brel    = (const float*)d_in[9];
    const float* Wo      = (const float*)d_in[10];
    const float* bo      = (const float*)d_in[11];
    const float* Wa      = (const float*)d_in[12];
    const float* ba      = (const float*)d_in[13];

    float* out0 = (float*)d_out;
    float* out1 = out0 + (size_t)NB * 3072 * 512;

    char* w = (char*)d_ws;
    ushort* EB     = (ushort*)w; w += (size_t)VOCAB * D * 2;
    ushort* WT     = (ushort*)w; w += (size_t)12 * WT_BLK * 2;
    ushort* PREB   = (ushort*)w; w += (size_t)9 * PRE_BLK * 2;
    ushort* feat   = (ushort*)w; w += (size_t)M_ROWS * 1024 * 2;
    int*    cnt    = (int*)   w; w += (size_t)32768 * 4;
    int*    offs   = (int*)   w; w += (size_t)32769 * 4;
    int*    cursor = (int*)   w; w += (size_t)32768 * 4;
    int*    lists  = (int*)   w; w += (size_t)65536 * 4;

    // L1: emb cvt + weight transpose + csr zero
    k_setup<<<dim3(4224), dim3(256), 0, stream>>>(emb, EB, Wsbj, Wobj, Wrel, Wo, Wa, WT, cnt);
    // L2: csr count
    k_csr_count<<<dim3(128), dim3(256), 0, stream>>>(ssg_rel, cnt);
    // L3: csr scan
    k_csr_scan<<<dim3(1), dim3(1024), 0, stream>>>(cnt, offs, cursor);
    // L4: PREB = E @ {9 blocks} (bf16)  ||  csr fill
    k_pre_fill<<<dim3(704), dim3(256), 0, stream>>>(EB, WT, PREB, ssg_rel, cursor, lists);
    // L5: sbj_f lookup layer -> feat lo
    k_sbj<<<dim3(M_ROWS / 2), dim3(256), 0, stream>>>(ssg_rel, ssg_obj, PREB, bsbj, feat);
    // L6: obj_f GEMM (256^2 pipelined) -> feat hi
    k_gemm8<1><<<dim3(256), dim3(512), 0, stream>>>(feat, WT, PREB, ssg_rel, ssg_obj,
                                                    bobj, feat, nullptr, nullptr);
    // L7: rel_f GEMM (256^2 pipelined) -> out0 + rel mask
    k_gemm8<2><<<dim3(256), dim3(512), 0, stream>>>(feat, WT, PREB, ssg_rel, ssg_obj,
                                                    brel, nullptr, out0, out1);
    // L8: per-object pass: node gather + att + obj/att masks
    k_objpass<<<dim3(M_ROWS / 2), dim3(256), 0, stream>>>(ssg_obj, ssg_att, offs, lists,
                                                          feat, PREB, bo, ba, out0, out1);
}